// Round 18
// baseline (762.254 us; speedup 1.0000x reference)
//
#include <hip/hip_runtime.h>
#include <math.h>

// R17 = R16 + (a) register-resident FF: F^T = mfma32(A=W1-A-pack, B=h-frag);
//   C-frag(F^T)-as-A == F feeds FF2 as mfma16 with W2T packs (mirrors O-proj).
//   FB + its DS ops eliminated; per-wave slot = HB (2432B) only.
//   (b) NS=2 seq interleave at 16 waves (LDS 104KB): FF/O frag loads shared
//   across the pair; attention per-u sequential (register pressure cap).

typedef __attribute__((ext_vector_type(8))) short s8v;
typedef __attribute__((ext_vector_type(4))) short s4v;
typedef __attribute__((ext_vector_type(4))) float f4v;
typedef __attribute__((ext_vector_type(4))) unsigned int u4v;

#define MFMA32(A, B, C) __builtin_amdgcn_mfma_f32_16x16x32_bf16((A), (B), (C), 0, 0, 0)
#define MFMA16(A, B, C) __builtin_amdgcn_mfma_f32_16x16x16bf16_1k((A), (B), (C), 0, 0, 0)

static __device__ __forceinline__ unsigned short f2b(float f) {
  return __builtin_bit_cast(unsigned short, (__bf16)f);
}
static __device__ __forceinline__ float b2f(unsigned short h) {
  return __builtin_bit_cast(float, ((unsigned)h) << 16);
}
static __device__ __forceinline__ s4v c4(f4v v) {
  s4v r;
  r[0] = (short)f2b(v[0]); r[1] = (short)f2b(v[1]);
  r[2] = (short)f2b(v[2]); r[3] = (short)f2b(v[3]);
  return r;
}

// ---- ws layout (bytes) ----
// [0)       B-pack 1KB tiles T=0..191 (qkv/ow/ff1/ff2 B-op; ff regions unused)
// [196608)  A-pack 1KB tiles T=192..223 (Wq/Wk A-op)
// [229376)  WO16 512B tiles E=0..31  (Wo^T MFMA16 B-op)
// [245760)  W1A 1KB tiles T2=0..63  (ff1 A-op: T2 = l*32 + ft*2 + kk)
// [311296)  W2T 512B tiles E2=0..127 (ff2^T MFMA16 B-op: E2 = l*64 + ft*4 + jo)
// total 376832
__global__ __launch_bounds__(256) void wpack(
    const float* __restrict__ qkv_w, const float* __restrict__ ow,
    const float* __restrict__ ff1_w, const float* __restrict__ ff2_w,
    unsigned int* __restrict__ ws) {
  int gid = blockIdx.x * 256 + threadIdx.x;   // 112 blocks -> tIdx 0..447
  int tIdx = gid >> 6, lane = gid & 63;
  int ln = lane & 15, grp = lane >> 4;
  if (tIdx < 224) {
    const float* src;
    if (tIdx < 48) {
      int l = tIdx / 24, r = tIdx % 24, kk = r / 12, j = r % 12;
      src = qkv_w + l * 12288 + (j * 16 + ln) * 64 + kk * 32 + grp * 8;
    } else if (tIdx < 64) {
      int u = tIdx - 48, l = u / 8, r = u % 8, kk = r / 4, j = r % 4;
      src = ow + l * 4096 + (j * 16 + ln) * 64 + kk * 32 + grp * 8;
    } else if (tIdx < 128) {
      int u = tIdx - 64, l = u / 32, r = u % 32, kk = r / 16, j = r % 16;
      src = ff1_w + l * 16384 + (j * 16 + ln) * 64 + kk * 32 + grp * 8;
    } else if (tIdx < 192) {
      int u = tIdx - 128, l = u / 32, r = u % 32, kk = r / 4, j = r % 4;
      src = ff2_w + l * 16384 + (j * 16 + ln) * 256 + kk * 32 + grp * 8;
    } else {
      int u = tIdx - 192, l = u / 16, r = u % 16, mat = r / 8, q = r % 8, jo = q / 2, kk = q % 2;
      src = qkv_w + l * 12288 + mat * 4096 + (jo * 16 + ln) * 64 + kk * 32 + grp * 8;
    }
    unsigned p[4];
#pragma unroll
    for (int e = 0; e < 4; ++e)
      p[e] = (unsigned)f2b(src[2 * e]) | ((unsigned)f2b(src[2 * e + 1]) << 16);
    u4v val = {p[0], p[1], p[2], p[3]};
    *(u4v*)(ws + (size_t)gid * 4) = val;
  } else if (tIdx < 256) {
    int E = tIdx - 224, l = E / 16, r = E % 16, hh = r / 4, jo = r % 4;
    const float* src = ow + l * 4096 + (jo * 16 + ln) * 64 + hh * 16 + grp * 4;
    unsigned lo = (unsigned)f2b(src[0]) | ((unsigned)f2b(src[1]) << 16);
    unsigned hi = (unsigned)f2b(src[2]) | ((unsigned)f2b(src[3]) << 16);
    *(uint2*)((char*)ws + 229376 + E * 512 + lane * 8) = make_uint2(lo, hi);
  } else if (tIdx < 320) {
    int u2 = tIdx - 256, l = u2 / 32, r = u2 % 32, ft = r / 2, kk = r % 2;
    const float* src = ff1_w + l * 16384 + (ft * 16 + ln) * 64 + kk * 32 + grp * 8;
    unsigned p[4];
#pragma unroll
    for (int e = 0; e < 4; ++e)
      p[e] = (unsigned)f2b(src[2 * e]) | ((unsigned)f2b(src[2 * e + 1]) << 16);
    *(u4v*)((char*)ws + 245760 + u2 * 1024 + lane * 16) = (u4v){p[0], p[1], p[2], p[3]};
  } else if (tIdx < 448) {
    int E = tIdx - 320, l = E / 64, r = E % 64, ft = r / 4, jo = r % 4;
    const float* src = ff2_w + l * 16384 + (jo * 16 + ln) * 256 + ft * 16 + grp * 4;
    unsigned lo = (unsigned)f2b(src[0]) | ((unsigned)f2b(src[1]) << 16);
    unsigned hi = (unsigned)f2b(src[2]) | ((unsigned)f2b(src[3]) << 16);
    *(uint2*)((char*)ws + 311296 + E * 512 + lane * 8) = make_uint2(lo, hi);
  }
}

__global__ __launch_bounds__(1024) void prithvi_fused(
    const float* __restrict__ x,     const float* __restrict__ conv_w,
    const float* __restrict__ bn_g,  const float* __restrict__ bn_b,
    const float* __restrict__ bn_m,  const float* __restrict__ bn_v,
    const float* __restrict__ w_in,  const float* __restrict__ qkv_b,
    const float* __restrict__ ob,    const float* __restrict__ ln1_g,
    const float* __restrict__ ln1_b, const float* __restrict__ ff1_b,
    const float* __restrict__ ff2_b, const float* __restrict__ ln2_g,
    const float* __restrict__ ln2_b, const float* __restrict__ w_out,
    const float* __restrict__ b_out, const float* __restrict__ ws,
    float* __restrict__ out)
{
  // 24576B g2 + 16 waves x 2 x 2432B HB slots + 4352B peL = 106752
  __shared__ __align__(16) char smem[106752];
  unsigned short* g2 = (unsigned short*)smem;   // [256 sl][12 t][4 c] bf16
  char* twb = smem + 24576;
  float* peL = (float*)(smem + 102400);          // [16 t][stride 68] fp32

  const int sp = blockIdx.x;
  const int tid = threadIdx.x, lane = tid & 63, wave = tid >> 6;

  // ---- pe table ----
  {
    int t_ = tid >> 6, d_ = tid & 63;
    float freq = expf(-(float)(d_ & ~1) * (9.210340371976184f / 64.f));
    float a = freq * (float)t_;
    peL[t_ * 68 + d_] = (d_ & 1) ? cosf(a) : sinf(a);
  }

  // ---------------- conv: 1 oc/thread, x staged 4 passes ----
  {
    float* stg = (float*)twb;   // 12288B
    float acc[12];
#pragma unroll
    for (int t = 0; t < 12; ++t) acc[t] = 0.f;
    const int c_ = tid >> 8, jj = tid & 255;
    const int oc = c_ * 256 + jj;
    const float* wrow = conv_w + (size_t)oc * 1024;
#pragma unroll 1
    for (int p = 0; p < 4; ++p) {
      for (int ch2 = tid; ch2 < 3072; ch2 += 1024) {
        int e = ch2 / 12, t = ch2 - 12 * e;
        stg[t * 256 + e] = x[(size_t)((p * 256 + e) * 12 + t) * 256 + sp];
      }
      __syncthreads();
      for (int eb = 0; eb < 256; eb += 4) {
        float4 w4 = *(const float4*)(wrow + p * 256 + eb);
#pragma unroll
        for (int t = 0; t < 12; ++t) {
          float4 xv = *(const float4*)&stg[t * 256 + eb];
          acc[t] = fmaf(xv.x, w4.x, acc[t]);
          acc[t] = fmaf(xv.y, w4.y, acc[t]);
          acc[t] = fmaf(xv.z, w4.z, acc[t]);
          acc[t] = fmaf(xv.w, w4.w, acc[t]);
        }
      }
      __syncthreads();
    }
    float sc = bn_g[oc] * rsqrtf(bn_v[oc] + 1e-5f);
    float sh = fmaf(-bn_m[oc], sc, bn_b[oc]);
#pragma unroll
    for (int t = 0; t < 12; ++t) {
      float z = fmaf(acc[t], sc, sh);
      g2[jj * 48 + t * 4 + c_] = f2b(0.5f * z * (1.f + erff(z * 0.70710678118654752f)));
    }
  }
  __syncthreads();   // g2 + peL read-only; twb free for HB slots

  // ---------------- phase 3: NS=2, 16 waves ----------------
  const int ln = lane & 15, grp = lane >> 4;
  char* HB[2] = {twb + wave * 4864, twb + wave * 4864 + 2432};
  const u4v* WS = (const u4v*)ws;
#define BT(T) __builtin_bit_cast(s8v, WS[(T) * 64 + lane])
#define BT2(T2) BT(240 + (T2))
#define WO16(E) __builtin_bit_cast(s4v, *(const uint2*)((const char*)ws + 229376 + (E) * 512 + lane * 8))
#define W2T(E2) WO16(160 + (E2))
#define STROW(BUF, ROW, COL, VAL) \
  ((unsigned short*)(BUF))[(ROW) * 76 + (COL)] = (VAL)

  const float bo0 = b_out[0];

#pragma unroll 1
  for (int itr = 0; itr < 8; ++itr) {
    const int sl0 = wave * 16 + itr * 2;
    f4v v[2][4];

    // ---- h0 (fp32 C-frag) -> HB bf16, both seqs ----
    {
      int tb = (grp < 3) ? grp * 4 : 0;
#pragma unroll
      for (int u = 0; u < 2; ++u) {
        const int sl = sl0 + u;
#pragma unroll
        for (int i = 0; i < 4; ++i) {
          uint2 gu = *(const uint2*)(g2 + sl * 48 + (tb + i) * 4);
          float g0 = b2f((unsigned short)(gu.x & 0xffff));
          float g1 = b2f((unsigned short)(gu.x >> 16));
          float g2v = b2f((unsigned short)(gu.y & 0xffff));
          float g3 = b2f((unsigned short)(gu.y >> 16));
#pragma unroll
          for (int j = 0; j < 4; ++j) {
            float4 wi = *(const float4*)(w_in + (j * 16 + ln) * 4);
            float peij = peL[(grp * 4 + i) * 68 + j * 16 + ln];
            v[u][j][i] = fmaf(g0, wi.x, fmaf(g1, wi.y,
                         fmaf(g2v, wi.z, fmaf(g3, wi.w, peij))));
          }
        }
#pragma unroll
        for (int i = 0; i < 4; ++i)
#pragma unroll
          for (int j = 0; j < 4; ++j)
            STROW(HB[u], grp * 4 + i, j * 16 + ln, f2b(v[u][j][i]));
      }
    }

#pragma unroll 1
    for (int l = 0; l < 2; ++l) {
      const f4v z4 = {0.f, 0.f, 0.f, 0.f};
      s4v Ot[2][4];
      // ---- fused QKV + attention, per-u sequential (register cap) ----
#pragma unroll
      for (int u = 0; u < 2; ++u) {
        s8v a0 = *(const s8v*)(HB[u] + ln * 152 + grp * 16);
        s8v a1 = *(const s8v*)(HB[u] + ln * 152 + 64 + grp * 16);
#pragma unroll
        for (int hh = 0; hh < 4; ++hh) {
          float4 bq = *(const float4*)(qkv_b + l * 192 + hh * 16 + grp * 4);
          f4v cq = {bq.x, bq.y, bq.z, bq.w};
          cq = MFMA32(BT(192 + l * 16 + hh * 2 + 0), a0, cq);
          cq = MFMA32(BT(192 + l * 16 + hh * 2 + 1), a1, cq);
          float4 bk = *(const float4*)(qkv_b + l * 192 + 64 + hh * 16 + grp * 4);
          f4v ck = {bk.x, bk.y, bk.z, bk.w};
          ck = MFMA32(BT(192 + l * 16 + 8 + hh * 2 + 0), a0, ck);
          ck = MFMA32(BT(192 + l * 16 + 8 + hh * 2 + 1), a1, ck);
          float bb = qkv_b[l * 192 + 128 + hh * 16 + ln];
          f4v cv = {bb, bb, bb, bb};
          cv = MFMA32(a0, BT(l * 24 + 8 + hh), cv);
          cv = MFMA32(a1, BT(l * 24 + 20 + hh), cv);
          s4v q4 = c4(cq), k4 = c4(ck), v4 = c4(cv);
          f4v sc = MFMA16(k4, q4, z4);   // lane: score(q=ln, k=grp*4+i)
          float e0, e1, e2, e3;
          if (grp == 3) { e0 = e1 = e2 = e3 = 0.f; }
          else {
            e0 = __expf(sc[0] * 0.25f); e1 = __expf(sc[1] * 0.25f);
            e2 = __expf(sc[2] * 0.25f); e3 = __expf(sc[3] * 0.25f);
          }
          float sm = (e0 + e1) + (e2 + e3);
          sm += __shfl_xor(sm, 16);
          sm += __shfl_xor(sm, 32);
          float inv = __builtin_amdgcn_rcpf(sm);
          s4v aP;
          aP[0] = (short)f2b(e0 * inv); aP[1] = (short)f2b(e1 * inv);
          aP[2] = (short)f2b(e2 * inv); aP[3] = (short)f2b(e3 * inv);
          Ot[u][hh] = c4(MFMA16(v4, aP, z4));
        }
      }
      // ---- O-proj: frags shared across u ----
      {
#pragma unroll
        for (int jo = 0; jo < 4; ++jo) {
          float bb = ob[l * 64 + jo * 16 + ln];
          f4v bb4 = {bb, bb, bb, bb};
#pragma unroll
          for (int u = 0; u < 2; ++u) v[u][jo] += bb4;
        }
#pragma unroll
        for (int hh = 0; hh < 4; ++hh) {
          s4v wo0 = WO16(l * 16 + hh * 4 + 0);
          s4v wo1 = WO16(l * 16 + hh * 4 + 1);
          s4v wo2 = WO16(l * 16 + hh * 4 + 2);
          s4v wo3 = WO16(l * 16 + hh * 4 + 3);
#pragma unroll
          for (int u = 0; u < 2; ++u) {
            v[u][0] = MFMA16(Ot[u][hh], wo0, v[u][0]);
            v[u][1] = MFMA16(Ot[u][hh], wo1, v[u][1]);
            v[u][2] = MFMA16(Ot[u][hh], wo2, v[u][2]);
            v[u][3] = MFMA16(Ot[u][hh], wo3, v[u][3]);
          }
        }
      }
      // ---- LN1 -> HB ----
      {
        const float* gp = ln1_g + l * 64;
        const float* bp = ln1_b + l * 64;
#pragma unroll
        for (int i = 0; i < 4; ++i) {
#pragma unroll
          for (int u = 0; u < 2; ++u) {
            float sm = v[u][0][i] + v[u][1][i] + v[u][2][i] + v[u][3][i];
            sm += __shfl_xor(sm, 1); sm += __shfl_xor(sm, 2);
            sm += __shfl_xor(sm, 4); sm += __shfl_xor(sm, 8);
            float mean = sm * 0.015625f;
            float q = 0.f;
#pragma unroll
            for (int j = 0; j < 4; ++j) { float d = v[u][j][i] - mean; q = fmaf(d, d, q); }
            q += __shfl_xor(q, 1); q += __shfl_xor(q, 2);
            q += __shfl_xor(q, 4); q += __shfl_xor(q, 8);
            float rs = rsqrtf(q * 0.015625f + 1e-5f);
#pragma unroll
            for (int j = 0; j < 4; ++j) {
              float nv = fmaf((v[u][j][i] - mean) * rs, gp[j * 16 + ln], bp[j * 16 + ln]);
              v[u][j][i] = nv;
              STROW(HB[u], grp * 4 + i, j * 16 + ln, f2b(nv));
            }
          }
        }
      }
      // ---- FF: register-resident; F^T tiles, frags shared across u ----
      {
        s8v ha0[2], ha1[2];
#pragma unroll
        for (int u = 0; u < 2; ++u) {
          ha0[u] = *(const s8v*)(HB[u] + ln * 152 + grp * 16);
          ha1[u] = *(const s8v*)(HB[u] + ln * 152 + 64 + grp * 16);
        }
#pragma unroll
        for (int jo = 0; jo < 4; ++jo) {
          float bb = ff2_b[l * 64 + jo * 16 + ln];
          f4v bb4 = {bb, bb, bb, bb};
#pragma unroll
          for (int u = 0; u < 2; ++u) v[u][jo] += bb4;
        }
#pragma unroll
        for (int ft = 0; ft < 16; ++ft) {
          s8v wa0 = BT2(l * 32 + ft * 2 + 0);
          s8v wa1 = BT2(l * 32 + ft * 2 + 1);
          float4 b4 = *(const float4*)(ff1_b + l * 256 + ft * 16 + grp * 4);
          s4v w2j0 = W2T(l * 64 + ft * 4 + 0);
          s4v w2j1 = W2T(l * 64 + ft * 4 + 1);
          s4v w2j2 = W2T(l * 64 + ft * 4 + 2);
          s4v w2j3 = W2T(l * 64 + ft * 4 + 3);
#pragma unroll
          for (int u = 0; u < 2; ++u) {
            f4v c = {b4.x, b4.y, b4.z, b4.w};
            c = MFMA32(wa0, ha0[u], c);    // F^T tile: rows f, cols t
            c = MFMA32(wa1, ha1[u], c);
#pragma unroll
            for (int i = 0; i < 4; ++i) c[i] = fmaxf(c[i], 0.f);
            s4v fv = c4(c);                 // F^T-frag-as-A == F
            v[u][0] = MFMA16(fv, w2j0, v[u][0]);
            v[u][1] = MFMA16(fv, w2j1, v[u][1]);
            v[u][2] = MFMA16(fv, w2j2, v[u][2]);
            v[u][3] = MFMA16(fv, w2j3, v[u][3]);
          }
        }
      }
      // ---- LN2 (store to HB only if another layer follows) ----
      {
        const float* gp = ln2_g + l * 64;
        const float* bp = ln2_b + l * 64;
#pragma unroll
        for (int i = 0; i < 4; ++i) {
#pragma unroll
          for (int u = 0; u < 2; ++u) {
            float sm = v[u][0][i] + v[u][1][i] + v[u][2][i] + v[u][3][i];
            sm += __shfl_xor(sm, 1); sm += __shfl_xor(sm, 2);
            sm += __shfl_xor(sm, 4); sm += __shfl_xor(sm, 8);
            float mean = sm * 0.015625f;
            float q = 0.f;
#pragma unroll
            for (int j = 0; j < 4; ++j) { float d = v[u][j][i] - mean; q = fmaf(d, d, q); }
            q += __shfl_xor(q, 1); q += __shfl_xor(q, 2);
            q += __shfl_xor(q, 4); q += __shfl_xor(q, 8);
            float rs = rsqrtf(q * 0.015625f + 1e-5f);
#pragma unroll
            for (int j = 0; j < 4; ++j) {
              float nv = fmaf((v[u][j][i] - mean) * rs, gp[j * 16 + ln], bp[j * 16 + ln]);
              v[u][j][i] = nv;
              if (l == 0) STROW(HB[u], grp * 4 + i, j * 16 + ln, f2b(nv));
            }
          }
        }
      }
    } // layer

    // ---- head: mean over t, dot w_out, sigmoid (both seqs) ----
#pragma unroll
    for (int u = 0; u < 2; ++u) {
      float dp = 0.f;
#pragma unroll
      for (int j = 0; j < 4; ++j) {
        float c0 = (grp < 3) ? (v[u][j][0] + v[u][j][1] + v[u][j][2] + v[u][j][3]) : 0.f;
        c0 += __shfl_xor(c0, 16);
        c0 += __shfl_xor(c0, 32);
        dp = fmaf(c0, w_out[j * 16 + ln], dp);
      }
      dp += __shfl_xor(dp, 1);
      dp += __shfl_xor(dp, 2);
      dp += __shfl_xor(dp, 4);
      dp += __shfl_xor(dp, 8);
      if (lane == 0) {
        const int sl = sl0 + u;
        float logit = dp * (1.f / 12.f) + bo0;
        int hf = ((sp >> 4) << 4) | (sl >> 4);
        int wf = ((sp & 15) << 4) | (sl & 15);
        out[hf * 256 + wf] = 1.f / (1.f + expf(-logit));
      }
    }
  } // seq loop
#undef BT
#undef BT2
#undef WO16
#undef W2T
#undef STROW
}

extern "C" void kernel_launch(void* const* d_in, const int* in_sizes, int n_in,
                              void* d_out, int out_size, void* d_ws, size_t ws_size,
                              hipStream_t stream) {
  (void)in_sizes; (void)n_in; (void)out_size; (void)ws_size;
  wpack<<<112, 256, 0, stream>>>(
      (const float*)d_in[7],  (const float*)d_in[9],
      (const float*)d_in[13], (const float*)d_in[15], (unsigned int*)d_ws);
  prithvi_fused<<<256, 1024, 0, stream>>>(
      (const float*)d_in[0],  (const float*)d_in[1],  (const float*)d_in[2],
      (const float*)d_in[3],  (const float*)d_in[4],  (const float*)d_in[5],
      (const float*)d_in[6],  (const float*)d_in[8],  (const float*)d_in[10],
      (const float*)d_in[11], (const float*)d_in[12], (const float*)d_in[14],
      (const float*)d_in[16], (const float*)d_in[17], (const float*)d_in[18],
      (const float*)d_in[19], (const float*)d_in[20], (const float*)d_ws,
      (float*)d_out);
}